// Round 4
// baseline (30.054 us; speedup 1.0000x reference)
//
#include <hip/hip_runtime.h>
#include <math.h>

#define IN_DIMS 128
#define OUT_PER_B (IN_DIMS * 9)
#define EPB 4              // batch elements per (persistent) block

// Raw barrier: drain LDS ops only; leave global loads (vmcnt) IN FLIGHT across
// the barrier so cross-element prefetch survives (__syncthreads would drain vmcnt(0)).
__device__ __forceinline__ void bar_lds() {
    asm volatile("s_waitcnt lgkmcnt(0)" ::: "memory");
    __builtin_amdgcn_s_barrier();
    asm volatile("" ::: "memory");
}

// Block = 512 threads; processes EPB consecutive batch elements.
// t -> c = t>>2 (channel), s = t&3 (quarter). Load k: float4 at byte
// offset 16*s + 64*k of channel c => lanes 4c..4c+3 cover whole 64-B lines.
// emb[3a+cc][h][w] = A[a][w]*B[cc][h] exactly (von-Mises x gaussian separate);
// A[a][w]=emb[3a][0][w], B[cc][h]=emb[cc][h][0] scales outputs by emb[0][0][0]>0,
// which cancels in the L2 norm.
__global__ __launch_bounds__(512) void ese_kernel(
        const float* __restrict__ x,     // (B, 128, 8, 8)
        const float* __restrict__ emb,   // (9, 8, 8)
        float* __restrict__ out)         // (B, 1152)
{
    __shared__ float s_out[OUT_PER_B];
    __shared__ float s_red[8];

    const int t = threadIdx.x;
    const int c = t >> 2;            // channel 0..127
    const int s = t & 3;             // quarter 0..3
    const int wb = (s & 1) * 4;      // w-base: 0 or 4
    const int hb = s >> 1;           // h = 2k + hb

    // emb constant slices -> registers, once per block (amortized over EPB).
    float4 sAv[3];
#pragma unroll
    for (int a = 0; a < 3; ++a)
        sAv[a] = *reinterpret_cast<const float4*>(&emb[(3 * a) * 64 + wb]);
    float sBv[3][4];
#pragma unroll
    for (int cc = 0; cc < 3; ++cc)
#pragma unroll
        for (int k = 0; k < 4; ++k)
            sBv[cc][k] = emb[cc * 64 + (2 * k + hb) * 8];

    const size_t b0 = (size_t)blockIdx.x * EPB;
    const float4* __restrict__ xp =
        reinterpret_cast<const float4*>(x + (b0 * IN_DIMS + c) * 64);
    // per-element stride in float4 units: 128*64/4 = 2048

    float4 v[4], vn[4];
#pragma unroll
    for (int k = 0; k < 4; ++k) v[k] = xp[s + 4 * k];

    for (int e = 0; e < EPB; ++e) {
        float acc[9];
#pragma unroll
        for (int j = 0; j < 9; ++j) acc[j] = 0.0f;

#pragma unroll
        for (int k = 0; k < 4; ++k) {
#pragma unroll
            for (int a = 0; a < 3; ++a) {
                const float u = v[k].x * sAv[a].x + v[k].y * sAv[a].y
                              + v[k].z * sAv[a].z + v[k].w * sAv[a].w;
#pragma unroll
                for (int cc = 0; cc < 3; ++cc)
                    acc[3 * a + cc] += u * sBv[cc][k];
            }
        }

        // Prefetch next element NOW; raw barriers below keep these in flight.
        if (e + 1 < EPB) {
            const float4* __restrict__ xq = xp + (size_t)(e + 1) * 2048;
#pragma unroll
            for (int k = 0; k < 4; ++k) vn[k] = xq[s + 4 * k];
        }

        // Merge the 4 quarter-lanes of each channel (all 4 end with full sums).
#pragma unroll
        for (int off = 1; off <= 2; off <<= 1)
#pragma unroll
            for (int j = 0; j < 9; ++j)
                acc[j] += __shfl_xor(acc[j], off, 64);

        // Block-wide sum of squares.
        float ss = 0.0f;
#pragma unroll
        for (int j = 0; j < 9; ++j) ss += acc[j] * acc[j];
#pragma unroll
        for (int off = 4; off <= 32; off <<= 1)
            ss += __shfl_xor(ss, off, 64);
        if ((t & 63) == 0) s_red[t >> 6] = ss;
        bar_lds();
        float total = 0.0f;
#pragma unroll
        for (int r = 0; r < 8; ++r) total += s_red[r];
        const float rn = 1.0f / sqrtf(total + 1e-10f);

        // Stage normalized outputs (writer lane s==0; dword stride 9 conflict-free).
        if (s == 0) {
#pragma unroll
            for (int j = 0; j < 9; ++j) s_out[c * 9 + j] = acc[j] * rn;
        }
        bar_lds();

        float4* __restrict__ ob4 =
            reinterpret_cast<float4*>(out + (b0 + e) * OUT_PER_B);
        if (t < OUT_PER_B / 4)
            ob4[t] = reinterpret_cast<const float4*>(s_out)[t];
        // s_out/s_red reuse next iteration is fenced by the next bar_lds()es:
        // every thread's LDS reads complete (lgkmcnt(0)) before it enters a
        // barrier, and the next writes happen only after that barrier.

#pragma unroll
        for (int k = 0; k < 4; ++k) v[k] = vn[k];
    }
}

extern "C" void kernel_launch(void* const* d_in, const int* in_sizes, int n_in,
                              void* d_out, int out_size, void* d_ws, size_t ws_size,
                              hipStream_t stream) {
    const float* x   = (const float*)d_in[0];
    const float* emb = (const float*)d_in[1];
    float* out       = (float*)d_out;

    const int B = in_sizes[0] / (IN_DIMS * 64);   // 4096
    ese_kernel<<<B / EPB, 512, 0, stream>>>(x, emb, out);
}

// Round 5
// 28.294 us; speedup vs baseline: 1.0622x; 1.0622x over previous
//
#include <hip/hip_runtime.h>
#include <math.h>

#define IN_DIMS 128
#define OUT_PER_B (IN_DIMS * 9)

// Block = 512 threads = one batch element (R2 structure: independent one-shot
// blocks pipeline best — persistent/EPB variants measured slower).
// t -> c = t>>2 (channel), s = t&3 (quarter). Load k: float4 at byte offset
// 16*s + 64*k of channel c => lanes 4c..4c+3 cover whole 64-B lines (1 req/line).
// emb[3a+cc][h][w] = A[a][w]*B[cc][h] exactly (von-Mises x gaussian separable);
// A[a][w]=emb[3a][0][w], B[cc][h]=emb[cc][h][0] scales outputs by emb[0][0][0]>0,
// which cancels in the L2 norm.
// SINGLE barrier per block: stage unnormalized outputs + ss partials before one
// __syncthreads; readers apply the norm during the store.
__global__ __launch_bounds__(512) void ese_kernel(
        const float* __restrict__ x,     // (B, 128, 8, 8)
        const float* __restrict__ emb,   // (9, 8, 8)
        float* __restrict__ out)         // (B, 1152)
{
    __shared__ float s_out[OUT_PER_B];   // unnormalized, read back as float4
    __shared__ float s_red[8];           // per-wave ss partials (read as 2x float4)

    const int b = blockIdx.x;
    const int t = threadIdx.x;
    const int c = t >> 2;            // channel 0..127
    const int s = t & 3;             // quarter 0..3
    const int wb = (s & 1) * 4;      // w-base: 0 or 4
    const int hb = s >> 1;           // h = 2k + hb

    // Streaming loads first (in flight during emb setup).
    const float4* __restrict__ xp =
        reinterpret_cast<const float4*>(x + ((size_t)b * IN_DIMS + c) * 64);
    float4 v[4];
#pragma unroll
    for (int k = 0; k < 4; ++k) v[k] = xp[s + 4 * k];

    // emb constant slices -> registers (24 dwords, L1/L2-resident).
    float4 sAv[3];
#pragma unroll
    for (int a = 0; a < 3; ++a)
        sAv[a] = *reinterpret_cast<const float4*>(&emb[(3 * a) * 64 + wb]);
    float sBv[3][4];
#pragma unroll
    for (int cc = 0; cc < 3; ++cc)
#pragma unroll
        for (int k = 0; k < 4; ++k)
            sBv[cc][k] = emb[cc * 64 + (2 * k + hb) * 8];

    float acc[9];
#pragma unroll
    for (int j = 0; j < 9; ++j) acc[j] = 0.0f;

#pragma unroll
    for (int k = 0; k < 4; ++k) {
#pragma unroll
        for (int a = 0; a < 3; ++a) {
            const float u = v[k].x * sAv[a].x + v[k].y * sAv[a].y
                          + v[k].z * sAv[a].z + v[k].w * sAv[a].w;
#pragma unroll
            for (int cc = 0; cc < 3; ++cc)
                acc[3 * a + cc] += u * sBv[cc][k];
        }
    }

    // Merge the 4 quarter-lanes of each channel (all 4 end with full sums).
#pragma unroll
    for (int off = 1; off <= 2; off <<= 1)
#pragma unroll
        for (int j = 0; j < 9; ++j)
            acc[j] += __shfl_xor(acc[j], off, 64);

    // Stage unnormalized outputs (writer lane s==0; dword stride 9 conflict-free).
    if (s == 0) {
#pragma unroll
        for (int j = 0; j < 9; ++j) s_out[c * 9 + j] = acc[j];
    }

    // Block-wide sum of squares partials.
    float ss = 0.0f;
#pragma unroll
    for (int j = 0; j < 9; ++j) ss += acc[j] * acc[j];
#pragma unroll
    for (int off = 4; off <= 32; off <<= 1)
        ss += __shfl_xor(ss, off, 64);
    if ((t & 63) == 0) s_red[t >> 6] = ss;

    __syncthreads();   // the ONLY barrier

    const float4 r0 = reinterpret_cast<const float4*>(s_red)[0];
    const float4 r1 = reinterpret_cast<const float4*>(s_red)[1];
    const float total = ((r0.x + r0.y) + (r0.z + r0.w))
                      + ((r1.x + r1.y) + (r1.z + r1.w));
    const float rn = 1.0f / sqrtf(total + 1e-10f);

    // Normalize at read time; 288 contiguous float4 stores.
    float4* __restrict__ ob4 = reinterpret_cast<float4*>(out + (size_t)b * OUT_PER_B);
    if (t < OUT_PER_B / 4) {
        float4 o = reinterpret_cast<const float4*>(s_out)[t];
        o.x *= rn; o.y *= rn; o.z *= rn; o.w *= rn;
        ob4[t] = o;
    }
}

extern "C" void kernel_launch(void* const* d_in, const int* in_sizes, int n_in,
                              void* d_out, int out_size, void* d_ws, size_t ws_size,
                              hipStream_t stream) {
    const float* x   = (const float*)d_in[0];
    const float* emb = (const float*)d_in[1];
    float* out       = (float*)d_out;

    const int B = in_sizes[0] / (IN_DIMS * 64);   // 4096
    ese_kernel<<<B, 512, 0, stream>>>(x, emb, out);
}